// Round 1
// baseline (257.823 us; speedup 1.0000x reference)
//
#include <hip/hip_runtime.h>

typedef __attribute__((ext_vector_type(8))) short bf16x8;
typedef __attribute__((ext_vector_type(4))) float f32x4;
typedef unsigned short u16;

#define NN 8192
#define FD 256

__device__ __forceinline__ u16 f2bf(float f) {
  union { float f; unsigned u; } v; v.f = f;
  unsigned r = v.u + 0x7FFF + ((v.u >> 16) & 1);
  return (u16)(r >> 16);
}
__device__ __forceinline__ float bf2f(u16 u) {
  union { unsigned u; float f; } v; v.u = ((unsigned)u) << 16;
  return v.f;
}

// ---- K1: Wh = h @ W, stored transposed: whT[c][r] (bf16) ----
__global__ __launch_bounds__(256) void k_wh(const float* __restrict__ h,
                                            const float* __restrict__ W,
                                            u16* __restrict__ whT) {
  int tid = threadIdx.x;
  int lane = tid & 63;
  int wv = tid >> 6;
  int r0 = blockIdx.x * 64 + (wv >> 1) * 32;
  int c0 = blockIdx.y * 64 + (wv & 1) * 32;
  int lr = lane & 15;
  int q = lane >> 4;

  f32x4 acc[2][2] = {};
  for (int kk = 0; kk < FD; kk += 32) {
    int kb = kk + q * 8;
    bf16x8 a[2], b[2];
#pragma unroll
    for (int m = 0; m < 2; m++) {
      const float* p = h + (size_t)(r0 + m * 16 + lr) * FD + kb;
      f32x4 x0 = *(const f32x4*)p;
      f32x4 x1 = *(const f32x4*)(p + 4);
      bf16x8 t;
      t[0] = (short)f2bf(x0[0]); t[1] = (short)f2bf(x0[1]);
      t[2] = (short)f2bf(x0[2]); t[3] = (short)f2bf(x0[3]);
      t[4] = (short)f2bf(x1[0]); t[5] = (short)f2bf(x1[1]);
      t[6] = (short)f2bf(x1[2]); t[7] = (short)f2bf(x1[3]);
      a[m] = t;
    }
#pragma unroll
    for (int n = 0; n < 2; n++) {
      int col = c0 + n * 16 + lr;
      const float* p = W + (size_t)kb * FD + col;
      bf16x8 t;
#pragma unroll
      for (int e = 0; e < 8; e++) t[e] = (short)f2bf(p[(size_t)e * FD]);
      b[n] = t;
    }
#pragma unroll
    for (int m = 0; m < 2; m++)
#pragma unroll
      for (int n = 0; n < 2; n++)
        acc[m][n] = __builtin_amdgcn_mfma_f32_16x16x32_bf16(a[m], b[n], acc[m][n], 0, 0, 0);
  }
#pragma unroll
  for (int m = 0; m < 2; m++)
#pragma unroll
    for (int n = 0; n < 2; n++) {
      int gc = c0 + n * 16 + lr;
      int gr = r0 + m * 16 + q * 4;
      ushort4 st;
      st.x = f2bf(acc[m][n][0]);
      st.y = f2bf(acc[m][n][1]);
      st.z = f2bf(acc[m][n][2]);
      st.w = f2bf(acc[m][n][3]);
      *(ushort4*)(whT + (size_t)gc * NN + gr) = st;
    }
}

// ---- K2: bf16 casts of h, w_ih, w_hh (row-major preserved) ----
__global__ __launch_bounds__(256) void k_cast(const float* __restrict__ h,
                                              const float* __restrict__ wih,
                                              const float* __restrict__ whh,
                                              u16* __restrict__ hb,
                                              u16* __restrict__ wihb,
                                              u16* __restrict__ whhb) {
  int g = blockIdx.x * 256 + threadIdx.x;
  const int hG = NN * FD / 4;
  const int wG = 768 * FD / 4;
  const float* sp;
  u16* dp;
  int off;
  if (g < hG) { sp = h; dp = hb; off = g; }
  else if (g < hG + wG) { sp = wih; dp = wihb; off = g - hG; }
  else { sp = whh; dp = whhb; off = g - hG - wG; }
  f32x4 x = *(const f32x4*)(sp + (size_t)off * 4);
  ushort4 y;
  y.x = f2bf(x[0]); y.y = f2bf(x[1]); y.z = f2bf(x[2]); y.w = f2bf(x[3]);
  *(ushort4*)(dp + (size_t)off * 4) = y;
}

// ---- K3: src_i = Wh_i . a[:F], dst_i = Wh_i . a[F:] (reads whT coalesced) ----
__global__ __launch_bounds__(256) void k_srcdst(const u16* __restrict__ whT,
                                                const float* __restrict__ a,
                                                float* __restrict__ src,
                                                float* __restrict__ dst) {
  __shared__ float p1[4][64];
  __shared__ float p2[4][64];
  int lane = threadIdx.x & 63;
  int wv = threadIdx.x >> 6;
  int i = blockIdx.x * 64 + lane;
  float s1 = 0.f, s2 = 0.f;
#pragma unroll 4
  for (int f = wv * 64; f < wv * 64 + 64; f++) {
    float wh = bf2f(whT[(size_t)f * NN + i]);
    s1 += wh * a[f];
    s2 += wh * a[256 + f];
  }
  p1[wv][lane] = s1;
  p2[wv][lane] = s2;
  __syncthreads();
  if (threadIdx.x < 64) {
    int ii = blockIdx.x * 64 + threadIdx.x;
    src[ii] = p1[0][threadIdx.x] + p1[1][threadIdx.x] + p1[2][threadIdx.x] + p1[3][threadIdx.x];
    dst[ii] = p2[0][threadIdx.x] + p2[1][threadIdx.x] + p2[2][threadIdx.x] + p2[3][threadIdx.x];
  }
}

// ---- K4: fused masked-softmax attention + PV GEMM ----
// Block: 32 rows, 512 threads (8 waves x 32 cols). Single pass over adj.
// P_ij = adj_ij * exp(lrelu(src_i + dst_j))   (no max-subtraction; bounded)
// h_prime_i = (1/l_i) * sum_j P_ij * Wh_j ;  l_i = sum_j P_ij
__global__ __launch_bounds__(512) void k_att(const float* __restrict__ adj,
                                             const u16* __restrict__ whT,
                                             const float* __restrict__ src,
                                             const float* __restrict__ dst,
                                             u16* __restrict__ hpb) {
  __shared__ u16 Pl[2][32][72];  // 64 data cols + pad to 72 (16B-aligned rows, 2-way banks)
  __shared__ float lred[32];
  int tid = threadIdx.x;
  int i0 = blockIdx.x * 32;
  int sr = tid >> 4;          // staging row 0..31
  int sc = (tid & 15) * 4;    // staging col group
  const float* adjRow = adj + (size_t)(i0 + sr) * NN;
  float srcv = src[i0 + sr];
  float lsum = 0.f;
  int lane = tid & 63;
  int wv = tid >> 6;          // 8 waves, 32 output cols each
  int c0 = wv * 32;
  int lr = lane & 15;
  int q = lane >> 4;
  f32x4 acc[2][2] = {};
  f32x4 ra0, rd0, ra1, rd1;   // 2-deep prefetch registers

#define LOADR(S, A, D)                                   \
  {                                                      \
    int j = (S) * 64 + sc;                               \
    A = *(const f32x4*)(adjRow + j);                     \
    D = *(const f32x4*)(dst + j);                        \
  }
#define PSTG(A, D, B)                                                   \
  {                                                                     \
    float p0, p1, p2, p3;                                               \
    { float x = srcv + D[0]; x = fmaxf(x, 0.2f * x); p0 = A[0] * __expf(x); } \
    { float x = srcv + D[1]; x = fmaxf(x, 0.2f * x); p1 = A[1] * __expf(x); } \
    { float x = srcv + D[2]; x = fmaxf(x, 0.2f * x); p2 = A[2] * __expf(x); } \
    { float x = srcv + D[3]; x = fmaxf(x, 0.2f * x); p3 = A[3] * __expf(x); } \
    lsum += (p0 + p1) + (p2 + p3);                                      \
    ushort4 st;                                                         \
    st.x = f2bf(p0); st.y = f2bf(p1); st.z = f2bf(p2); st.w = f2bf(p3); \
    *(ushort4*)&Pl[B][sr][sc] = st;                                     \
  }
#define CMP(S, B)                                                                              \
  {                                                                                            \
    _Pragma("unroll")                                                                          \
    for (int kk = 0; kk < 2; kk++) {                                                           \
      bf16x8 aF0 = *(const bf16x8*)&Pl[B][lr][kk * 32 + q * 8];                                \
      bf16x8 aF1 = *(const bf16x8*)&Pl[B][16 + lr][kk * 32 + q * 8];                           \
      bf16x8 bF0 = *(const bf16x8*)(whT + (size_t)(c0 + lr) * NN + (S) * 64 + kk * 32 + q * 8);\
      bf16x8 bF1 = *(const bf16x8*)(whT + (size_t)(c0 + 16 + lr) * NN + (S) * 64 + kk * 32 + q * 8); \
      acc[0][0] = __builtin_amdgcn_mfma_f32_16x16x32_bf16(aF0, bF0, acc[0][0], 0, 0, 0);       \
      acc[0][1] = __builtin_amdgcn_mfma_f32_16x16x32_bf16(aF0, bF1, acc[0][1], 0, 0, 0);       \
      acc[1][0] = __builtin_amdgcn_mfma_f32_16x16x32_bf16(aF1, bF0, acc[1][0], 0, 0, 0);       \
      acc[1][1] = __builtin_amdgcn_mfma_f32_16x16x32_bf16(aF1, bF1, acc[1][1], 0, 0, 0);       \
    }                                                                                          \
  }

  const int NS = NN / 64;  // 128 K-steps of 64
  LOADR(0, ra0, rd0);
  LOADR(1, ra1, rd1);
  PSTG(ra0, rd0, 0);
  __syncthreads();
  for (int s2 = 0; s2 < NS; s2 += 2) {
    if (s2 + 2 < NS) LOADR(s2 + 2, ra0, rd0);
    PSTG(ra1, rd1, 1);      // stage step s2+1 -> buf 1
    CMP(s2, 0);             // compute step s2 from buf 0
    __syncthreads();
    if (s2 + 3 < NS) LOADR(s2 + 3, ra1, rd1);
    if (s2 + 2 < NS) PSTG(ra0, rd0, 0);  // stage step s2+2 -> buf 0
    CMP(s2 + 1, 1);
    __syncthreads();
  }
#pragma unroll
  for (int m = 1; m < 16; m <<= 1) lsum += __shfl_xor(lsum, m);
  if ((tid & 15) == 0) lred[sr] = lsum;
  __syncthreads();
#pragma unroll
  for (int m = 0; m < 2; m++) {
#pragma unroll
    for (int j = 0; j < 4; j++) {
      int rl = m * 16 + q * 4 + j;
      float inv = 1.0f / lred[rl];
#pragma unroll
      for (int n = 0; n < 2; n++) {
        int col = c0 + n * 16 + lr;
        hpb[(size_t)(i0 + rl) * FD + col] = f2bf(acc[m][n][j] * inv);
      }
    }
  }
#undef LOADR
#undef PSTG
#undef CMP
}

// ---- K5: fused GRUCell: gi = h'@w_ih^T+b_ih, gh = h@w_hh^T+b_hh, gates, blend ----
__global__ __launch_bounds__(256) void k_gru(const u16* __restrict__ hpb,
                                             const u16* __restrict__ hb,
                                             const u16* __restrict__ wihb,
                                             const u16* __restrict__ whhb,
                                             const float* __restrict__ bih,
                                             const float* __restrict__ bhh,
                                             const float* __restrict__ h,
                                             float* __restrict__ out) {
  int tid = threadIdx.x;
  int lane = tid & 63;
  int wv = tid >> 6;
  int i0 = blockIdx.x * 32;
  int lr = lane & 15;
  int q = lane >> 4;
  int c = blockIdx.y * 64 + wv * 16 + lr;
  f32x4 gi[3][2] = {};
  f32x4 gh[3][2] = {};
  for (int kk = 0; kk < FD; kk += 32) {
    int kb = kk + q * 8;
    bf16x8 ap[2], ah[2], bi[3], bh[3];
#pragma unroll
    for (int m = 0; m < 2; m++) {
      ap[m] = *(const bf16x8*)(hpb + (size_t)(i0 + m * 16 + lr) * FD + kb);
      ah[m] = *(const bf16x8*)(hb + (size_t)(i0 + m * 16 + lr) * FD + kb);
    }
#pragma unroll
    for (int g = 0; g < 3; g++) {
      bi[g] = *(const bf16x8*)(wihb + (size_t)(g * 256 + c) * FD + kb);
      bh[g] = *(const bf16x8*)(whhb + (size_t)(g * 256 + c) * FD + kb);
    }
#pragma unroll
    for (int g = 0; g < 3; g++)
#pragma unroll
      for (int m = 0; m < 2; m++) {
        gi[g][m] = __builtin_amdgcn_mfma_f32_16x16x32_bf16(ap[m], bi[g], gi[g][m], 0, 0, 0);
        gh[g][m] = __builtin_amdgcn_mfma_f32_16x16x32_bf16(ah[m], bh[g], gh[g][m], 0, 0, 0);
      }
  }
  float bir = bih[c], biz = bih[256 + c], bin = bih[512 + c];
  float bhr = bhh[c], bhz = bhh[256 + c], bhn = bhh[512 + c];
#pragma unroll
  for (int m = 0; m < 2; m++)
#pragma unroll
    for (int j = 0; j < 4; j++) {
      int row = i0 + m * 16 + q * 4 + j;
      float rv = gi[0][m][j] + bir + gh[0][m][j] + bhr;
      float zv = gi[1][m][j] + biz + gh[1][m][j] + bhz;
      float r = 1.f / (1.f + __expf(-rv));
      float z = 1.f / (1.f + __expf(-zv));
      float nx = gi[2][m][j] + bin + r * (gh[2][m][j] + bhn);
      float n = 1.f - 2.f / (__expf(2.f * nx) + 1.f);
      float hv = h[(size_t)row * FD + c];
      out[(size_t)row * FD + c] = (1.f - z) * n + z * hv;
    }
}

extern "C" void kernel_launch(void* const* d_in, const int* in_sizes, int n_in,
                              void* d_out, int out_size, void* d_ws, size_t ws_size,
                              hipStream_t stream) {
  const float* h   = (const float*)d_in[0];
  const float* adj = (const float*)d_in[1];
  const float* W   = (const float*)d_in[2];
  const float* a   = (const float*)d_in[3];
  const float* wih = (const float*)d_in[4];
  const float* whh = (const float*)d_in[5];
  const float* bih = (const float*)d_in[6];
  const float* bhh = (const float*)d_in[7];
  float* out = (float*)d_out;

  char* ws = (char*)d_ws;
  u16* whT  = (u16*)(ws);                 // 256*8192*2 = 4 MB  (Wh transposed)
  u16* hpb  = (u16*)(ws + 4194304);       // 8192*256*2 = 4 MB  (h_prime bf16)
  u16* hb   = (u16*)(ws + 8388608);       // 8192*256*2 = 4 MB  (h bf16)
  u16* wihb = (u16*)(ws + 12582912);      // 768*256*2
  u16* whhb = (u16*)(ws + 12976128);      // 768*256*2
  float* srcv = (float*)(ws + 13369344);  // 8192*4
  float* dstv = (float*)(ws + 13402112);  // 8192*4

  k_wh<<<dim3(128, 4), 256, 0, stream>>>(h, W, whT);
  k_cast<<<2432, 256, 0, stream>>>(h, wih, whh, hb, wihb, whhb);
  k_srcdst<<<128, 256, 0, stream>>>(whT, a, srcv, dstv);
  k_att<<<256, 512, 0, stream>>>(adj, whT, srcv, dstv, hpb);
  k_gru<<<dim3(256, 4), 256, 0, stream>>>(hpb, hb, wihb, whhb, bih, bhh, h, out);
}